// Round 8
// baseline (6277.421 us; speedup 1.0000x reference)
//
#include <hip/hip_runtime.h>
#include <hip/hip_fp16.h>
#include <math.h>

#define BB 128
#define SS 512
#define TT 128
#define FF 64
#define HH 1024

#define NBLK 256   // 4 b-groups x 64 j-blocks
#define NTHR 256   // 4 waves = 4 k-quarters, full N=64 per wave

typedef _Float16 half8 __attribute__((ext_vector_type(8)));
typedef float    f32x16 __attribute__((ext_vector_type(16)));
typedef unsigned long long u64;

// ---- fast transcendentals (rel err ~1e-6 << fp16 noise floor) ----
__device__ __forceinline__ float rcpf(float x){ return __builtin_amdgcn_rcpf(x); }
__device__ __forceinline__ float sigm(float x){ return rcpf(1.f + __expf(-x)); }
__device__ __forceinline__ float tfast(float x){
  float a = fabsf(x);
  float e = __expf(-2.f*a);
  float t = (1.f - e) * rcpf(1.f + e);
  return copysignf(t, x);
}

// ---- IF$-coherent accessors (sc1: bypass per-XCD L2) ----
__device__ __forceinline__ u64 aload64(const u64* p){
  return __hip_atomic_load(p, __ATOMIC_RELAXED, __HIP_MEMORY_SCOPE_AGENT);
}
__device__ __forceinline__ void astore64(u64* p, u64 v){
  __hip_atomic_store(p, v, __ATOMIC_RELAXED, __HIP_MEMORY_SCOPE_AGENT);
}

// ---- pre-kernels: fp32 -> fp16 ----
__global__ __launch_bounds__(256) void cvt_plain(const float* __restrict__ s,
                                                 ushort* __restrict__ d, int n){
  for (int i = blockIdx.x*256 + threadIdx.x; i < n; i += gridDim.x*256)
    d[i] = __half_as_ushort(__float2half(s[i]));
}
// src [b][s][f] -> src16T [s][f>>3][b][f&7]
__global__ __launch_bounds__(256) void cvt_src(const float* __restrict__ s,
                                               ushort* __restrict__ d){
  for (int i = blockIdx.x*256 + threadIdx.x; i < BB*SS*FF; i += gridDim.x*256){
    int f = i & 63, st = (i >> 6) & 511, b = i >> 15;
    d[(((size_t)st*8 + (f>>3))*128 + b)*8 + (f&7)] = __half_as_ushort(__float2half(s[i]));
  }
}

// h slots: u64 hsl[2][128][128][4] = [parity][o=j>>3][b][(j>>1)&3], val = epoch<<32 | 2xfp16
// pred slots: u64 ppsl[2][4][64][32] = [parity][btile][jblk][m],    val = epoch<<32 | f32bits
__global__ __launch_bounds__(NTHR, 1) void seq_kernel(
  const float*  __restrict__ tgt,
  const _Float16* __restrict__ src16T,  // [512][8][128][8]
  const _Float16* __restrict__ wih16,   // [4H][64]
  const _Float16* __restrict__ ewhh16,  // [4H][1024]
  const _Float16* __restrict__ dwhh16,  // [4H][1024]
  const float* __restrict__ ebih, const float* __restrict__ ebhh,
  const float* __restrict__ dWih,
  const float* __restrict__ dbih, const float* __restrict__ dbhh,
  const float* __restrict__ fcW, const float* __restrict__ fcb,
  float* __restrict__ out, u64* hsl, u64* ppsl)
{
  __shared__ float Ct4[4][32][68];   // [wk][m][n], pad 68: conflict-free
  __shared__ float xacc[2][32];
  __shared__ float predsum[32];

  const int tid = threadIdx.x;
  const int wk  = tid >> 6;              // k-quarter
  const int l   = tid & 63;
  const int nl  = l & 31, ko = l >> 5;   // lane row / k-octet
  const int btile = blockIdx.x >> 6;
  const int jblk  = blockIdx.x & 63;
  const int m = tid & 31, q = tid >> 5;  // epilogue: (b=m, jj=2q,2q+1)

  // ---- B fragments to registers ----
  half8 Bh[32];
  #pragma unroll
  for (int s = 0; s < 16; s++)
    #pragma unroll
    for (int h = 0; h < 2; h++){
      int nn = h*32 + nl;
      size_t grow = (size_t)((nn>>4)*HH + jblk*16 + (nn&15));
      Bh[s*2+h] = *(const half8*)(ewhh16 + grow*HH + wk*256 + s*16 + ko*8);
    }
  half8 Bx[2];
  #pragma unroll
  for (int h = 0; h < 2; h++){
    int nn = h*32 + nl;
    size_t grow = (size_t)((nn>>4)*HH + jblk*16 + (nn&15));
    Bx[h] = *(const half8*)(wih16 + grow*FF + wk*16 + ko*8);
  }

  float ebv[8], wxv[8], fcwv[2];
  #pragma unroll
  for (int g = 0; g < 4; g++)
    #pragma unroll
    for (int u = 0; u < 2; u++){
      int jg = jblk*16 + 2*q + u;
      ebv[g*2+u] = ebih[g*HH + jg] + ebhh[g*HH + jg];
      wxv[g*2+u] = 0.f;
    }
  fcwv[0] = fcwv[1] = 0.f;
  const float fcb0v = fcb[0];

  if (jblk == 0 && tid < 32) out[(size_t)(btile*32 + tid)*TT] = 0.f;

  float cc0 = 0.f, cc1 = 0.f;

  for (int t = 0; t < SS + TT - 1; t++){
    const bool enc = (t < SS);
    f32x16 acc0, acc1;
    #pragma unroll
    for (int r = 0; r < 16; r++){ acc0[r] = 0.f; acc1[r] = 0.f; }

    if (t == SS){   // decoder switch (in-register)
      #pragma unroll
      for (int s = 0; s < 16; s++)
        #pragma unroll
        for (int h = 0; h < 2; h++){
          int nn = h*32 + nl;
          size_t grow = (size_t)((nn>>4)*HH + jblk*16 + (nn&15));
          Bh[s*2+h] = *(const half8*)(dwhh16 + grow*HH + wk*256 + s*16 + ko*8);
        }
      #pragma unroll
      for (int g = 0; g < 4; g++)
        #pragma unroll
        for (int u = 0; u < 2; u++){
          int jg = jblk*16 + 2*q + u;
          ebv[g*2+u] = dbih[g*HH + jg] + dbhh[g*HH + jg];
          wxv[g*2+u] = dWih[g*HH + jg];
        }
      fcwv[0] = fcW[jblk*16 + 2*q];
      fcwv[1] = fcW[jblk*16 + 2*q + 1];
    }

    // ---- issue full 16-frag A window (64 epoch-stamped u64 loads) ----
    u64 w[16][4];
    const u64* hb = hsl + ((size_t)((t&1)*128 + wk*32 + ko)*128 + btile*32 + nl)*4;
    if (t > 0){
      #pragma unroll
      for (int s = 0; s < 16; s++){
        const u64* bp = hb + (size_t)s*1024;   // o += 2 per s
        w[s][0]=aload64(bp); w[s][1]=aload64(bp+1);
        w[s][2]=aload64(bp+2); w[s][3]=aload64(bp+3);
      }
    }
    // decoder pred loads (latency hidden under h poll)
    u64 pv[8];
    const u64* pb = ppsl + ((size_t)((t+1)&1)*4 + btile)*2048 + (size_t)(q*8)*32 + m;
    if (!enc && t > SS){
      #pragma unroll
      for (int i = 0; i < 8; i++) pv[i] = aload64(pb + (size_t)i*32);
    }
    // encoder x-part (independent of h arrival)
    if (enc){
      half8 xa = *(const half8*)(src16T + (((size_t)t*8 + wk*2 + ko)*128 + btile*32 + nl)*8);
      acc0 = __builtin_amdgcn_mfma_f32_32x32x16_f16(xa, Bx[0], acc0, 0,0,0);
      acc1 = __builtin_amdgcn_mfma_f32_32x32x16_f16(xa, Bx[1], acc1, 0,0,0);
    }

    // ---- validate epochs; fast path = first sweep free; retries backed off ----
    if (t > 0){
      const unsigned e = (unsigned)t;
      bool allok = false;
      bool first = true;
      while (!allok){
        if (!first) __builtin_amdgcn_s_sleep(2);   // ~128cy backoff: don't flood IF$
        first = false;
        allok = true;
        #pragma unroll
        for (int s = 0; s < 16; s++){
          unsigned bad = ((unsigned)(w[s][0]>>32)^e) | ((unsigned)(w[s][1]>>32)^e)
                       | ((unsigned)(w[s][2]>>32)^e) | ((unsigned)(w[s][3]>>32)^e);
          if (bad){
            const u64* bp = hb + (size_t)s*1024;
            w[s][0]=aload64(bp); w[s][1]=aload64(bp+1);
            w[s][2]=aload64(bp+2); w[s][3]=aload64(bp+3);
            allok = false;
          }
        }
      }
      #pragma unroll
      for (int s = 0; s < 16; s++){
        union { unsigned d[4]; half8 v; } ua;
        ua.d[0]=(unsigned)w[s][0]; ua.d[1]=(unsigned)w[s][1];
        ua.d[2]=(unsigned)w[s][2]; ua.d[3]=(unsigned)w[s][3];
        acc0 = __builtin_amdgcn_mfma_f32_32x32x16_f16(ua.v, Bh[2*s],   acc0, 0,0,0);
        acc1 = __builtin_amdgcn_mfma_f32_32x32x16_f16(ua.v, Bh[2*s+1], acc1, 0,0,0);
      }
    }

    // ---- epilogue ----
    if (tid < 32) predsum[tid] = 0.f;
    if (tid >= 32 && tid < 64) xacc[(t+1)&1][tid-32] = 0.f;
    #pragma unroll
    for (int r = 0; r < 16; r++){
      int mr = (r & 3) + 8*(r >> 2) + 4*ko;     // C/D row map (m74/m101)
      Ct4[wk][mr][nl]      = acc0[r];
      Ct4[wk][mr][32 + nl] = acc1[r];
    }
    float xr_pre = 0.f;
    if (!enc){
      if (t == SS) xr_pre = tgt[(size_t)(btile*32 + m)*TT];
      else {
        const unsigned e = (unsigned)(t-1);
        bool ok = false;
        bool first = true;
        while (!ok){
          if (!first) __builtin_amdgcn_s_sleep(1);
          first = false;
          ok = true;
          #pragma unroll
          for (int i = 0; i < 8; i++)
            if ((unsigned)(pv[i]>>32) != e){ pv[i] = aload64(pb + (size_t)i*32); ok = false; }
        }
        float v = 0.f;
        #pragma unroll
        for (int i = 0; i < 8; i++) v += __uint_as_float((unsigned)pv[i]);
        atomicAdd(&xacc[t&1][m], v);
      }
    }
    __syncthreads();

    float xr = 0.f;
    if (!enc){
      if (t == SS) xr = xr_pre;
      else {
        xr = xacc[t&1][m] + fcb0v;
        if (jblk == 0 && tid < 32)
          out[(size_t)(btile*32 + tid)*TT + (t - SS)] = xacc[t&1][tid] + fcb0v;
      }
    }

    float gv[8];
    #pragma unroll
    for (int g = 0; g < 4; g++)
      #pragma unroll
      for (int u = 0; u < 2; u++){
        int n = g*16 + 2*q + u;
        float s2 = ((Ct4[0][m][n] + Ct4[1][m][n]) + (Ct4[2][m][n] + Ct4[3][m][n]))
                 + ebv[g*2+u];
        if (!enc) s2 += xr * wxv[g*2+u];
        gv[g*2+u] = s2;
      }
    float h2[2];
    #pragma unroll
    for (int u = 0; u < 2; u++){
      float si = sigm(gv[0+u]), sf = sigm(gv[2+u]), so = sigm(gv[6+u]);
      float tg = tfast(gv[4+u]);
      float c = u ? cc1 : cc0;
      c = sf*c + si*tg;
      if (u) cc1 = c; else cc0 = c;
      h2[u] = so * tfast(c);
    }
    {  // h(t+1): single epoch-stamped u64 store
      int o = jblk*2 + (q >> 2);
      u64 val = ((u64)(unsigned)(t+1) << 32)
              | (u64)((unsigned)__half_as_ushort(__float2half(h2[0]))
                    | ((unsigned)__half_as_ushort(__float2half(h2[1])) << 16));
      astore64(&hsl[((size_t)(((t+1)&1)*128 + o)*128 + btile*32 + m)*4 + (q&3)], val);
    }
    if (!enc){
      atomicAdd(&predsum[m], h2[0]*fcwv[0] + h2[1]*fcwv[1]);
      __syncthreads();
      if (tid < 32){
        u64 val = ((u64)(unsigned)t << 32) | (u64)__float_as_uint(predsum[tid]);
        astore64(&ppsl[((size_t)(t&1)*4 + btile)*2048 + (size_t)jblk*32 + tid], val);
      }
    }
    __syncthreads();   // protect Ct4/xacc/predsum reuse across steps
  }

  // ---- final column 127 = fc(h(127)): poll partials stamped t=638 (parity 0) ----
  if (jblk == 0){
    const u64* fb = ppsl + (size_t)btile*2048 + (size_t)(q*8)*32 + m;
    u64 fv[8];
    #pragma unroll
    for (int i = 0; i < 8; i++) fv[i] = aload64(fb + (size_t)i*32);
    const unsigned e = 638u;
    bool ok = false;
    bool first = true;
    while (!ok){
      if (!first) __builtin_amdgcn_s_sleep(1);
      first = false;
      ok = true;
      #pragma unroll
      for (int i = 0; i < 8; i++)
        if ((unsigned)(fv[i]>>32) != e){ fv[i] = aload64(fb + (size_t)i*32); ok = false; }
    }
    float v = 0.f;
    #pragma unroll
    for (int i = 0; i < 8; i++) v += __uint_as_float((unsigned)fv[i]);
    atomicAdd(&xacc[1][m], v);          // zeroed during t=638
    __syncthreads();
    if (tid < 32)
      out[(size_t)(btile*32 + tid)*TT + (TT-1)] = xacc[1][tid] + fcb0v;
  }
}

extern "C" void kernel_launch(void* const* d_in, const int* in_sizes, int n_in,
                              void* d_out, int out_size, void* d_ws, size_t ws_size,
                              hipStream_t stream){
  (void)in_sizes; (void)n_in; (void)out_size; (void)ws_size;
  const float* src  = (const float*)d_in[0];
  const float* tgt  = (const float*)d_in[1];
  const float* eWih = (const float*)d_in[2];
  const float* eWhh = (const float*)d_in[3];
  const float* ebih = (const float*)d_in[4];
  const float* ebhh = (const float*)d_in[5];
  const float* dWih = (const float*)d_in[6];
  const float* dWhh = (const float*)d_in[7];
  const float* dbih = (const float*)d_in[8];
  const float* dbhh = (const float*)d_in[9];
  const float* fcW  = (const float*)d_in[10];
  const float* fcb  = (const float*)d_in[11];
  float* out = (float*)d_out;

  // ws carve: poison 0xAA... never matches a valid epoch (<=639) -> no init needed
  u64*    hsl    = (u64*)d_ws;                 // 2*128*128*4 u64 = 1 MB
  ushort* src16T = (ushort*)(hsl + 131072);    // 8 MB
  ushort* wih16  = src16T + 4194304;           // 0.5 MB
  ushort* ewhh16 = wih16  + 262144;            // 8 MB
  ushort* dwhh16 = ewhh16 + 4194304;           // 8 MB
  u64*    ppsl   = (u64*)(dwhh16 + 4194304);   // 2*4*64*32 u64 = 128 KB

  cvt_src  <<<4096, 256, 0, stream>>>(src, src16T);
  cvt_plain<<<1024, 256, 0, stream>>>(eWih, wih16,  4*HH*FF);
  cvt_plain<<<4096, 256, 0, stream>>>(eWhh, ewhh16, 4*HH*HH);
  cvt_plain<<<4096, 256, 0, stream>>>(dWhh, dwhh16, 4*HH*HH);
  seq_kernel<<<dim3(NBLK), dim3(NTHR), 0, stream>>>(
      tgt, (const _Float16*)src16T, (const _Float16*)wih16,
      (const _Float16*)ewhh16, (const _Float16*)dwhh16,
      ebih, ebhh, dWih, dbih, dbhh, fcW, fcb, out, hsl, ppsl);
}

// Round 9
// 2640.992 us; speedup vs baseline: 2.3769x; 2.3769x over previous
//
#include <hip/hip_runtime.h>
#include <hip/hip_fp16.h>
#include <math.h>

#define BB 128
#define SS 512
#define TT 128
#define FF 64
#define HH 1024

#define NBT 8      // batch groups, M=16 each (independent barrier domains)
#define NJB 32     // j-blocks, N=128 each (4 gates x 32 j)
#define NBLK 256
#define NTHR 256   // 4 waves = 4 k-quarters (K=256), full N=128 per wave

typedef _Float16 half8 __attribute__((ext_vector_type(8)));
typedef float    f32x4 __attribute__((ext_vector_type(4)));
typedef unsigned long long u64;

// ---- fast transcendentals (rel err ~1e-6 << fp16 noise floor) ----
__device__ __forceinline__ float rcpf(float x){ return __builtin_amdgcn_rcpf(x); }
__device__ __forceinline__ float sigm(float x){ return rcpf(1.f + __expf(-x)); }
__device__ __forceinline__ float tfast(float x){
  float a = fabsf(x);
  float e = __expf(-2.f*a);
  float t = (1.f - e) * rcpf(1.f + e);
  return copysignf(t, x);
}

// ---- IF$-coherent accessors (sc1: bypass per-XCD L2) ----
__device__ __forceinline__ u64 aload64(const u64* p){
  return __hip_atomic_load(p, __ATOMIC_RELAXED, __HIP_MEMORY_SCOPE_AGENT);
}
__device__ __forceinline__ float aloadf(const float* p){
  return __hip_atomic_load(p, __ATOMIC_RELAXED, __HIP_MEMORY_SCOPE_AGENT);
}
__device__ __forceinline__ void astoref(float* p, float v){
  __hip_atomic_store(p, v, __ATOMIC_RELAXED, __HIP_MEMORY_SCOPE_AGENT);
}
__device__ __forceinline__ void astoreu(unsigned* p, unsigned v){
  __hip_atomic_store(p, v, __ATOMIC_RELAXED, __HIP_MEMORY_SCOPE_AGENT);
}

// ---- contention-free flag barrier (per btile: 32 flags) ----
__device__ __forceinline__ void bar_arrive(unsigned* flags, int jblk, unsigned* barno){
  asm volatile("s_waitcnt vmcnt(0)" ::: "memory");  // sc1 stores ack'd at IF$
  __syncthreads();
  ++(*barno);
  if (threadIdx.x == 0) astoreu(&flags[jblk], *barno);
}
__device__ __forceinline__ void bar_wait(const unsigned* flags, unsigned barno){
  if (threadIdx.x < 32){
    while (__hip_atomic_load(&flags[threadIdx.x], __ATOMIC_RELAXED,
                             __HIP_MEMORY_SCOPE_AGENT) < barno) {}
  }
  __syncthreads();
}

// ---- pre-kernels: fp32 -> fp16 ----
__global__ __launch_bounds__(256) void cvt_plain(const float* __restrict__ s,
                                                 ushort* __restrict__ d, int n){
  for (int i = blockIdx.x*256 + threadIdx.x; i < n; i += gridDim.x*256)
    d[i] = __half_as_ushort(__float2half(s[i]));
}
// src [b][s][f] -> src16T [s][f>>3][b][f&7]
__global__ __launch_bounds__(256) void cvt_src(const float* __restrict__ s,
                                               ushort* __restrict__ d){
  for (int i = blockIdx.x*256 + threadIdx.x; i < BB*SS*FF; i += gridDim.x*256){
    int f = i & 63, st = (i >> 6) & 511, b = i >> 15;
    d[(((size_t)st*8 + (f>>3))*128 + b)*8 + (f&7)] = __half_as_ushort(__float2half(s[i]));
  }
}

// h slots: ushort h16[2][o=128][b=128][8]  (o = j>>3, 16B-contiguous per (o,b))
// pred:    float ppsl[2][8 btile][32 jblk][16 m]
__global__ __launch_bounds__(NTHR, 1) void seq_kernel(
  const float*  __restrict__ tgt,
  const _Float16* __restrict__ src16T,  // [512][8][128][8]
  const _Float16* __restrict__ wih16,   // [4H][64]
  const _Float16* __restrict__ ewhh16,  // [4H][1024]
  const _Float16* __restrict__ dwhh16,  // [4H][1024]
  const float* __restrict__ ebih, const float* __restrict__ ebhh,
  const float* __restrict__ dWih,
  const float* __restrict__ dbih, const float* __restrict__ dbhh,
  const float* __restrict__ fcW, const float* __restrict__ fcb,
  float* __restrict__ out, ushort* h16u, float* ppsl, unsigned* barflags)
{
  __shared__ float Ct4[4][16][132];  // [wk][m][n], pad 132: <=2-way bank alias (free)
  __shared__ float xacc[2][16];
  __shared__ float predsum[16];

  const int tid = threadIdx.x;
  const int wk  = tid >> 6;              // k-quarter (K=256)
  const int l   = tid & 63;
  const int la  = l & 15, lq = l >> 4;   // frag: row/col-in-tile, k-octet-quarter
  const int btile = blockIdx.x >> 5;     // 0..7 (16 batch rows)
  const int jblk  = blockIdx.x & 31;     // 0..31 (32 j-columns)
  const int m = tid & 15, q = tid >> 4;  // epilogue: (b=m, j-pair 2q,2q+1), q 0..15
  unsigned* flags = barflags + btile*32;
  unsigned barno = 0;

  // ---- B fragments to registers: Bh[kc*8+nt], kc=k-chunk(32) in wave, nt=n-tile ----
  half8 Bh[64];
  #pragma unroll
  for (int kc = 0; kc < 8; kc++)
    #pragma unroll
    for (int nt = 0; nt < 8; nt++){
      size_t grow = (size_t)((nt>>1)*HH + jblk*32 + (nt&1)*16 + la);
      Bh[kc*8+nt] = *(const half8*)(ewhh16 + grow*HH + wk*256 + kc*32 + lq*8);
    }
  half8 Bx[8];
  if (wk < 2)
    #pragma unroll
    for (int nt = 0; nt < 8; nt++){
      size_t grow = (size_t)((nt>>1)*HH + jblk*32 + (nt&1)*16 + la);
      Bx[nt] = *(const half8*)(wih16 + grow*FF + wk*32 + lq*8);
    }

  float ebv[8], wxv[8], fcwv[2];
  #pragma unroll
  for (int g = 0; g < 4; g++)
    #pragma unroll
    for (int u = 0; u < 2; u++){
      int jg = jblk*32 + 2*q + u;
      ebv[g*2+u] = ebih[g*HH + jg] + ebhh[g*HH + jg];
      wxv[g*2+u] = 0.f;
    }
  fcwv[0] = fcwv[1] = 0.f;
  const float fcb0v = fcb[0];

  if (jblk == 0 && tid < 16) out[(size_t)(btile*16 + tid)*TT] = 0.f;
  bar_arrive(flags, jblk, &barno);

  float cc0 = 0.f, cc1 = 0.f;   // cell state in registers for all 639 steps

  for (int t = 0; t < SS + TT - 1; t++){
    const bool enc = (t < SS);
    f32x4 acc[8];
    #pragma unroll
    for (int nt = 0; nt < 8; nt++)
      #pragma unroll
      for (int r = 0; r < 4; r++) acc[nt][r] = 0.f;

    if (t == SS){   // decoder switch (in-register)
      #pragma unroll
      for (int kc = 0; kc < 8; kc++)
        #pragma unroll
        for (int nt = 0; nt < 8; nt++){
          size_t grow = (size_t)((nt>>1)*HH + jblk*32 + (nt&1)*16 + la);
          Bh[kc*8+nt] = *(const half8*)(dwhh16 + grow*HH + wk*256 + kc*32 + lq*8);
        }
      #pragma unroll
      for (int g = 0; g < 4; g++)
        #pragma unroll
        for (int u = 0; u < 2; u++){
          int jg = jblk*32 + 2*q + u;
          ebv[g*2+u] = dbih[g*HH + jg] + dbhh[g*HH + jg];
          wxv[g*2+u] = dWih[g*HH + jg];
        }
      fcwv[0] = fcW[jblk*32 + 2*q];
      fcwv[1] = fcW[jblk*32 + 2*q + 1];
    }

    // encoder x-part (waves 0,1 each K=32) before the wait
    if (enc && wk < 2){
      half8 xa = *(const half8*)(src16T +
                   (((size_t)t*8 + wk*4 + lq)*128 + btile*16 + la)*8);
      #pragma unroll
      for (int nt = 0; nt < 8; nt++)
        acc[nt] = __builtin_amdgcn_mfma_f32_16x16x32_f16(xa, Bx[nt], acc[nt], 0,0,0);
    }

    bar_wait(flags, barno);   // h(t)/pred(t-1) visible at IF$

    float pv0 = 0.f, pv1 = 0.f;
    if (!enc && t > SS){      // pred partial loads (latency hidden under h loads)
      const float* pp = ppsl + ((size_t)(((t+1)&1)*NBT + btile)*NJB)*16;
      pv0 = aloadf(pp + (size_t)q*16 + m);
      pv1 = aloadf(pp + (size_t)(q+16)*16 + m);
    }

    // ---- h K-loop: sc1 loads -> MFMA, no LDS, no syncs ----
    if (t > 0){
      u64 w0[8], w1[8];
      const ushort* hb = h16u + ((size_t)((t&1)*128 + wk*32)*128)*8;
      #pragma unroll
      for (int kc = 0; kc < 8; kc++){
        const u64* p = (const u64*)(hb + ((size_t)(kc*4+lq)*128 + btile*16 + la)*8);
        w0[kc] = aload64(p); w1[kc] = aload64(p+1);
      }
      #pragma unroll
      for (int kc = 0; kc < 8; kc++){
        union { u64 qq[2]; half8 v; } ua;
        ua.qq[0] = w0[kc]; ua.qq[1] = w1[kc];
        #pragma unroll
        for (int nt = 0; nt < 8; nt++)
          acc[nt] = __builtin_amdgcn_mfma_f32_16x16x32_f16(ua.v, Bh[kc*8+nt], acc[nt], 0,0,0);
      }
    }

    // ---- epilogue: 4-way k-reduce + gate transpose through LDS ----
    if (tid < 16) predsum[tid] = 0.f;
    if (tid >= 16 && tid < 32) xacc[(t+1)&1][tid-16] = 0.f;
    #pragma unroll
    for (int nt = 0; nt < 8; nt++)
      #pragma unroll
      for (int r = 0; r < 4; r++)
        Ct4[wk][lq*4 + r][nt*16 + la] = acc[nt][r];   // 16x16 C/D: col=la, row=lq*4+r
    float xr = 0.f;
    if (!enc){
      if (t == SS) xr = tgt[(size_t)(btile*16 + m)*TT];
      else atomicAdd(&xacc[t&1][m], pv0 + pv1);
    }
    __syncthreads();
    if (!enc && t > SS){
      xr = xacc[t&1][m] + fcb0v;
      if (jblk == 0 && tid < 16)
        out[(size_t)(btile*16 + tid)*TT + (t - SS)] = xacc[t&1][tid] + fcb0v;
    }

    float gv[8];
    #pragma unroll
    for (int g = 0; g < 4; g++)
      #pragma unroll
      for (int u = 0; u < 2; u++){
        int n = g*32 + 2*q + u;
        float s2 = ((Ct4[0][m][n] + Ct4[1][m][n]) + (Ct4[2][m][n] + Ct4[3][m][n]))
                 + ebv[g*2+u];
        if (!enc) s2 += xr * wxv[g*2+u];
        gv[g*2+u] = s2;
      }
    float h2[2];
    #pragma unroll
    for (int u = 0; u < 2; u++){
      float si = sigm(gv[0+u]), sf = sigm(gv[2+u]), so = sigm(gv[6+u]);
      float tg = tfast(gv[4+u]);
      float c = u ? cc1 : cc0;
      c = sf*c + si*tg;
      if (u) cc1 = c; else cc0 = c;
      h2[u] = so * tfast(c);
    }
    {  // h(t+1) store: packed dword (j=2q,2q+1 adjacent in 16B slot), sc1
      int o = jblk*4 + (q >> 2);
      unsigned hv = (unsigned)__half_as_ushort(__float2half(h2[0]))
                  | ((unsigned)__half_as_ushort(__float2half(h2[1])) << 16);
      astoreu((unsigned*)(h16u + ((size_t)(((t+1)&1)*128 + o)*128 + btile*16 + m)*8
                          + (q&3)*2), hv);
    }
    if (!enc){
      atomicAdd(&predsum[m], h2[0]*fcwv[0] + h2[1]*fcwv[1]);
      __syncthreads();
      if (tid < 16)
        astoref(ppsl + (((size_t)(t&1)*NBT + btile)*NJB + jblk)*16 + tid, predsum[tid]);
    }
    bar_arrive(flags, jblk, &barno);   // includes vmcnt-drain + syncthreads (LDS safe)
  }

  // ---- final column 127 = fc(h(127)): pred of t=638 at parity 0 ----
  if (jblk == 0){
    bar_wait(flags, barno);
    const float* pp = ppsl + ((size_t)btile*NJB)*16;
    float v = aloadf(pp + (size_t)q*16 + m) + aloadf(pp + (size_t)(q+16)*16 + m);
    atomicAdd(&xacc[1][m], v);        // zeroed during t=638
    __syncthreads();
    if (tid < 16)
      out[(size_t)(btile*16 + tid)*TT + (TT-1)] = xacc[1][tid] + fcb0v;
  }
}

extern "C" void kernel_launch(void* const* d_in, const int* in_sizes, int n_in,
                              void* d_out, int out_size, void* d_ws, size_t ws_size,
                              hipStream_t stream){
  (void)in_sizes; (void)n_in; (void)out_size; (void)ws_size;
  const float* src  = (const float*)d_in[0];
  const float* tgt  = (const float*)d_in[1];
  const float* eWih = (const float*)d_in[2];
  const float* eWhh = (const float*)d_in[3];
  const float* ebih = (const float*)d_in[4];
  const float* ebhh = (const float*)d_in[5];
  const float* dWih = (const float*)d_in[6];
  const float* dWhh = (const float*)d_in[7];
  const float* dbih = (const float*)d_in[8];
  const float* dbhh = (const float*)d_in[9];
  const float* fcW  = (const float*)d_in[10];
  const float* fcb  = (const float*)d_in[11];
  float* out = (float*)d_out;

  // ws carve (ushort units)
  ushort* h16    = (ushort*)d_ws;          // 2*128*128*8      = 262144
  ushort* src16T = h16    + 262144;        // 512*8*128*8      = 4194304
  ushort* wih16  = src16T + 4194304;       // 4096*64          = 262144
  ushort* ewhh16 = wih16  + 262144;        // 4096*1024        = 4194304
  ushort* dwhh16 = ewhh16 + 4194304;       // 4096*1024        = 4194304
  float*  ppsl   = (float*)(dwhh16 + 4194304);     // 2*8*32*16 = 8192 floats
  unsigned* barflags = (unsigned*)(ppsl + 8192);   // 8 btiles x 32 u32

  hipMemsetAsync(barflags, 0, NBT*NJB*sizeof(unsigned), stream);  // ws poisoned每call
  cvt_src  <<<4096, 256, 0, stream>>>(src, src16T);
  cvt_plain<<<1024, 256, 0, stream>>>(eWih, wih16,  4*HH*FF);
  cvt_plain<<<4096, 256, 0, stream>>>(eWhh, ewhh16, 4*HH*HH);
  cvt_plain<<<4096, 256, 0, stream>>>(dWhh, dwhh16, 4*HH*HH);
  seq_kernel<<<dim3(NBLK), dim3(NTHR), 0, stream>>>(
      tgt, (const _Float16*)src16T, (const _Float16*)wih16,
      (const _Float16*)ewhh16, (const _Float16*)dwhh16,
      ebih, ebhh, dWih, dbih, dbhh, fcW, fcb, out, h16, ppsl, barflags);
}